// Round 7
// baseline (305.654 us; speedup 1.0000x reference)
//
#include <hip/hip_runtime.h>
#include <cstddef>

// ---------------- problem constants (match reference) ----------------
#define NB   4
#define NN_  6
#define ND_  41
#define NFH  16
#define NFW  44
#define NC   64
#define NX0_ 200
#define NX1_ 200
#define NXY  (NX0_ * NX1_)                 // 40000
#define NCOL (NB * NN_ * ND_ * NFW)        // 43296 columns (each = 16 vertical pixels)
#define NCELL (NB * NXY)                   // 160000 BEV cells
#define CAP   48                           // max entries per cell (est. worst ~17)
#define QMAX  (64 * CAP)                   // per-tile queue bound (by construction)

// 3x3 inverse via adjugate. Exact in f32 for these inputs (validated).
__device__ __forceinline__ void inv3(const float* a, float* inv) {
    float c00 = __fsub_rn(__fmul_rn(a[4], a[8]), __fmul_rn(a[5], a[7]));
    float c01 = __fsub_rn(__fmul_rn(a[5], a[6]), __fmul_rn(a[3], a[8]));
    float c02 = __fsub_rn(__fmul_rn(a[3], a[7]), __fmul_rn(a[4], a[6]));
    float det = __fadd_rn(__fadd_rn(__fmul_rn(a[0], c00), __fmul_rn(a[1], c01)),
                          __fmul_rn(a[2], c02));
    inv[0] = __fdiv_rn(c00, det);
    inv[1] = __fdiv_rn(__fsub_rn(__fmul_rn(a[2], a[7]), __fmul_rn(a[1], a[8])), det);
    inv[2] = __fdiv_rn(__fsub_rn(__fmul_rn(a[1], a[5]), __fmul_rn(a[2], a[4])), det);
    inv[3] = __fdiv_rn(c01, det);
    inv[4] = __fdiv_rn(__fsub_rn(__fmul_rn(a[0], a[8]), __fmul_rn(a[2], a[6])), det);
    inv[5] = __fdiv_rn(__fsub_rn(__fmul_rn(a[2], a[3]), __fmul_rn(a[0], a[5])), det);
    inv[6] = __fdiv_rn(c02, det);
    inv[7] = __fdiv_rn(__fsub_rn(__fmul_rn(a[1], a[6]), __fmul_rn(a[0], a[7])), det);
    inv[8] = __fdiv_rn(__fsub_rn(__fmul_rn(a[0], a[4]), __fmul_rn(a[1], a[3])), det);
}

__global__ void setup_kernel(const float* __restrict__ rots,
                             const float* __restrict__ trans,
                             const float* __restrict__ intrins,
                             const float* __restrict__ post_rots,
                             const float* __restrict__ post_trans,
                             float* __restrict__ mats) {
    int t = threadIdx.x;
    if (t >= NB * NN_) return;
    const float* R  = rots      + t * 9;
    const float* K  = intrins   + t * 9;
    const float* PR = post_rots + t * 9;
    float Kinv[9], Pinv[9];
    inv3(K, Kinv);
    inv3(PR, Pinv);
    float* o = mats + t * 24;
    for (int i = 0; i < 3; ++i)
        for (int k = 0; k < 3; ++k) {
            float s = __fmul_rn(R[i * 3 + 0], Kinv[0 * 3 + k]);
            s = __fadd_rn(s, __fmul_rn(R[i * 3 + 1], Kinv[1 * 3 + k]));
            s = __fadd_rn(s, __fmul_rn(R[i * 3 + 2], Kinv[2 * 3 + k]));
            o[i * 3 + k] = s;
        }
    for (int i = 0; i < 9; ++i) o[9 + i] = Pinv[i];
    o[18] = trans[t * 3 + 0];
    o[19] = trans[t * 3 + 1];
    o[20] = trans[t * 3 + 2];
    o[21] = post_trans[t * 3 + 0];
    o[22] = post_trans[t * 3 + 1];
    o[23] = post_trans[t * 3 + 2];
}

// Fire-and-forget hardware FP32 atomic add (fallback path only).
__device__ __forceinline__ void hw_fadd(float* p, float v) {
    asm volatile("global_atomic_add_f32 %0, %1, off" : : "v"(p), "v"(v) : "memory");
}

// Voxel flat index (b*NXY + i0*NX1 + i1) for point (b,n,d,h,w), or -1.
// Numerics IDENTICAL to the passing rounds.
__device__ __forceinline__ int compute_idx(int b, int n, int d, int h, int w,
                                           const float* __restrict__ mats) {
    const float* mp = mats + (b * NN_ + n) * 24;

    float u   = (w == NFW - 1) ? 703.0f : (float)((double)w * (703.0 / 43.0));
    float v   = __fmul_rn((float)h, 17.0f);   // 255/15 == 17 exactly
    float dep = (float)(4 + d);               // arange(4,45,1): exact ints

    float f0 = __fsub_rn(u, mp[21]);
    float f1 = __fsub_rn(v, mp[22]);
    float f2 = __fsub_rn(dep, mp[23]);

    float q0 = __fadd_rn(__fadd_rn(__fmul_rn(mp[9],  f0), __fmul_rn(mp[10], f1)), __fmul_rn(mp[11], f2));
    float q1 = __fadd_rn(__fadd_rn(__fmul_rn(mp[12], f0), __fmul_rn(mp[13], f1)), __fmul_rn(mp[14], f2));
    float q2 = __fadd_rn(__fadd_rn(__fmul_rn(mp[15], f0), __fmul_rn(mp[16], f1)), __fmul_rn(mp[17], f2));

    float r0 = __fmul_rn(q0, q2);
    float r1 = __fmul_rn(q1, q2);

    float g0 = __fadd_rn(__fadd_rn(__fadd_rn(__fmul_rn(mp[0], r0), __fmul_rn(mp[1], r1)), __fmul_rn(mp[2], q2)), mp[18]);
    float g1 = __fadd_rn(__fadd_rn(__fadd_rn(__fmul_rn(mp[3], r0), __fmul_rn(mp[4], r1)), __fmul_rn(mp[5], q2)), mp[19]);
    float g2 = __fadd_rn(__fadd_rn(__fadd_rn(__fmul_rn(mp[6], r0), __fmul_rn(mp[7], r1)), __fmul_rn(mp[8], q2)), mp[20]);

    float s0 = __fdiv_rn(__fsub_rn(g0, -50.0f), 0.5f);
    float s1 = __fdiv_rn(__fsub_rn(g1, -50.0f), 0.5f);
    float s2 = __fdiv_rn(__fsub_rn(g2, -10.0f), 20.0f);
    s0 = fminf(fmaxf(s0, -1e6f), 1e6f);
    s1 = fminf(fmaxf(s1, -1e6f), 1e6f);
    s2 = fminf(fmaxf(s2, -1e6f), 1e6f);
    int i0 = (int)s0;   // trunc toward zero == jnp.trunc().astype(int32)
    int i1 = (int)s1;
    int i2 = (int)s2;
    if (i0 >= 0 && i0 < NX0_ && i1 >= 0 && i1 < NX1_ && i2 >= 0 && i2 < 1)
        return b * NXY + i0 * NX1_ + i1;
    return -1;
}

// Fused column pass: one 16-lane group per (b,n,d,w) column.
//  - lane l computes compute_idx for h=l (round-3 validated pattern)
//  - butterfly reduce -> vm (valid mask), vmin/vmax (cell agreement)
//  - append ONE list entry per column (lane 0), aux[cid] = vm
//  - streaming masked h-sum of x (round-3's exact accumulation tree)
//    -> colsum[cid] (256 B, coalesced). The 177 MB -> 11 MB reduction
//    happens HERE, stream-ordered — not in the cell-ordered gather
//    (round-5 mistake: gather re-walked 4 KB of x per entry).
__global__ __launch_bounds__(256) void colsum_build(const float* __restrict__ x,
                                                    const float* __restrict__ mats,
                                                    int* __restrict__ cnt,
                                                    unsigned* __restrict__ lists,
                                                    unsigned* __restrict__ aux,
                                                    float4* __restrict__ colsum) {
    int cid = blockIdx.x * 16 + (threadIdx.x >> 4);    // NCOL = 2706*16 exactly
    int l   = threadIdx.x & 15;
    int w = cid % NFW; int t = cid / NFW;
    int d = t % ND_;   t /= ND_;
    int n = t % NN_;   int b = t / NN_;

    int myidx = compute_idx(b, n, d, l, w, mats);      // h = l

    int vm   = (myidx >= 0) ? (1 << l) : 0;
    int vmin = (myidx >= 0) ? myidx : 0x7fffffff;
    int vmax = myidx;
    #pragma unroll
    for (int k = 1; k < 16; k <<= 1) {
        vm  |= __shfl_xor(vm,  k, 16);
        vmin = min(vmin, __shfl_xor(vmin, k, 16));
        vmax = max(vmax, __shfl_xor(vmax, k, 16));
    }
    if (vmax < 0) return;                              // whole column dropped
    bool allsame = (vmin == vmax);

    if (allsame) {                                     // the real path
        if (l == 0) {
            int slot = atomicAdd(&cnt[vmax], 1);
            if (slot < CAP)
                lists[(size_t)vmax * CAP + slot] = ((unsigned)vm << 16) | (unsigned)cid;
        }
    } else {                                           // safety net (unreachable)
        if (myidx >= 0) {
            int slot = atomicAdd(&cnt[myidx], 1);
            if (slot < CAP)
                lists[(size_t)myidx * CAP + slot] = (1u << (16 + l)) | (unsigned)cid;
        }
    }
    if (l == 0) aux[cid] = (unsigned)vm;

    // masked h-sum, replicating round-3's tree:
    // ((h0+h2+h4+h6)+(h1+h3+h5+h7)) + ((h8+..)+(h9+..))
    const float4* xp = (const float4*)
        (x + (((size_t)((b * NN_ + n) * ND_ + d) * NFH) * NFW + w) * NC) + l;
    const int HS = NFW * (NC / 4);

    float4 v[8];
    float4 A0 = make_float4(0.f, 0.f, 0.f, 0.f);
    float4 A1 = make_float4(0.f, 0.f, 0.f, 0.f);
    #pragma unroll
    for (int j = 0; j < 8; ++j) v[j] = xp[j * HS];
    #pragma unroll
    for (int j = 0; j < 8; j += 2) {
        float m0 = ((vm >> j) & 1) ? 1.0f : 0.0f;
        float m1 = ((vm >> (j + 1)) & 1) ? 1.0f : 0.0f;
        A0.x += v[j].x * m0;     A0.y += v[j].y * m0;
        A0.z += v[j].z * m0;     A0.w += v[j].w * m0;
        A1.x += v[j + 1].x * m1; A1.y += v[j + 1].y * m1;
        A1.z += v[j + 1].z * m1; A1.w += v[j + 1].w * m1;
    }
    float4 s0 = make_float4(A0.x + A1.x, A0.y + A1.y, A0.z + A1.z, A0.w + A1.w);

    float4 B0 = make_float4(0.f, 0.f, 0.f, 0.f);
    float4 B1 = make_float4(0.f, 0.f, 0.f, 0.f);
    #pragma unroll
    for (int j = 0; j < 8; ++j) v[j] = xp[(8 + j) * HS];
    #pragma unroll
    for (int j = 0; j < 8; j += 2) {
        float m0 = ((vm >> (8 + j)) & 1) ? 1.0f : 0.0f;
        float m1 = ((vm >> (9 + j)) & 1) ? 1.0f : 0.0f;
        B0.x += v[j].x * m0;     B0.y += v[j].y * m0;
        B0.z += v[j].z * m0;     B0.w += v[j].w * m0;
        B1.x += v[j + 1].x * m1; B1.y += v[j + 1].y * m1;
        B1.z += v[j + 1].z * m1; B1.w += v[j + 1].w * m1;
    }
    float4 s1 = make_float4(B0.x + B1.x, B0.y + B1.y, B0.z + B1.z, B0.w + B1.w);

    colsum[(size_t)cid * 16 + l] =
        make_float4(s0.x + s1.x, s0.y + s1.y, s0.z + s1.z, s0.w + s1.w);
}

// One block per (64-cell xy strip, b). Queue all entries of the strip,
// round-robin over 16 lane-groups. Per entry: 256 B read from colsum
// (16x less traffic than round 5's x re-walk), ds_add_f32 into the
// XOR-swizzled tile, then the validated coalesced write epilogue
// (writes every out element -> replaces output memset). Rare path
// (hmask != aux[cid], i.e. h-dependent cells): direct masked x read.
__global__ __launch_bounds__(256) void gather_bev(const float* __restrict__ x,
                                                  const int* __restrict__ cnt,
                                                  const unsigned* __restrict__ lists,
                                                  const unsigned* __restrict__ aux,
                                                  const float4* __restrict__ colsum,
                                                  float* __restrict__ out) {
    __shared__ float4 tile[64 * 16];          // [cell][c4 ^ ((cell>>2)&15)], 16 KB
    __shared__ unsigned short items[QMAX];    // (ci<<8)|e, 6 KB; bounded by construction
    __shared__ int qcount;

    int b   = blockIdx.y;
    int xy0 = blockIdx.x * 64;

    if (threadIdx.x == 0) qcount = 0;
    #pragma unroll
    for (int s = 0; s < 4; ++s)
        tile[s * 256 + threadIdx.x] = make_float4(0.f, 0.f, 0.f, 0.f);
    __syncthreads();

    if (threadIdx.x < 64) {
        int ci = threadIdx.x;
        int c  = cnt[b * NXY + xy0 + ci];
        c = c < CAP ? c : CAP;
        if (c > 0) {
            int base = atomicAdd(&qcount, c);
            for (int e = 0; e < c; ++e)
                items[base + e] = (unsigned short)((ci << 8) | e);
        }
    }
    __syncthreads();
    int total = qcount;

    int g = threadIdx.x >> 4;                 // lane-group 0..15
    int l = threadIdx.x & 15;                 // channel quad
    const int HS = NFW * (NC / 4);

    for (int i = g; i < total; i += 16) {
        unsigned it = items[i];
        int ci = it >> 8, e = it & 255;
        unsigned ent = lists[(size_t)(b * NXY + xy0 + ci) * CAP + e];
        int cid = ent & 0xffff;
        unsigned hmask = ent >> 16;

        float4 a;
        if (__builtin_expect(hmask == aux[cid], 1)) {
            a = colsum[(size_t)cid * 16 + l];          // 256 B per entry
        } else {
            // safety net: h-dependent cell -> masked direct x read
            int w = cid % NFW; int t2 = cid / NFW;
            int d = t2 % ND_;  t2 /= ND_;
            int n = t2 % NN_;
            const float4* xp = (const float4*)
                (x + (((size_t)((b * NN_ + n) * ND_ + d) * NFH) * NFW + w) * NC) + l;
            a = make_float4(0.f, 0.f, 0.f, 0.f);
            #pragma unroll
            for (int j = 0; j < 16; ++j) {
                if ((hmask >> j) & 1) {
                    float4 vv = xp[j * HS];
                    a.x += vv.x; a.y += vv.y; a.z += vv.z; a.w += vv.w;
                }
            }
        }

        float* tp = (float*)&tile[ci * 16 + (l ^ ((ci >> 2) & 15))];
        atomicAdd(tp + 0, a.x);   // ds_add_f32, no return
        atomicAdd(tp + 1, a.y);
        atomicAdd(tp + 2, a.z);
        atomicAdd(tp + 3, a.w);
    }
    __syncthreads();

    int lane = threadIdx.x & 63, wv = threadIdx.x >> 6;
    int q = lane & 15, lh = lane >> 4, i0 = q << 2;
    #pragma unroll
    for (int s = 0; s < 4; ++s) {
        int c  = s * 16 + wv * 4 + lh;        // covers 0..63 exactly once
        int c4 = c >> 2, cr = c & 3;
        float4 vv;
        vv.x = ((const float*)&tile[(i0 + 0) * 16 + (c4 ^ q)])[cr];
        vv.y = ((const float*)&tile[(i0 + 1) * 16 + (c4 ^ q)])[cr];
        vv.z = ((const float*)&tile[(i0 + 2) * 16 + (c4 ^ q)])[cr];
        vv.w = ((const float*)&tile[(i0 + 3) * 16 + (c4 ^ q)])[cr];
        *(float4*)(out + ((size_t)(b * NC + c)) * NXY + xy0 + i0) = vv;
    }
}

// ---------------- fallback (ws too small): direct-atomic path ----------------
__global__ __launch_bounds__(256) void col_pool_direct(const float* __restrict__ x,
                                                       const float* __restrict__ mats,
                                                       float* __restrict__ dst) {
    int cid = blockIdx.x * 8 + (threadIdx.x >> 5);
    int sub = threadIdx.x & 31;
    int l   = sub & 15;
    int hh  = sub >> 4;
    int w = cid % NFW; int t = cid / NFW;
    int d = t % ND_;   t /= ND_;
    int n = t % NN_;   int b = t / NN_;

    int myidx = compute_idx(b, n, d, l, w, mats);
    int idx8[8];
    #pragma unroll
    for (int j = 0; j < 8; ++j) idx8[j] = __shfl(myidx, hh * 8 + j, 32);

    int vmax = myidx;
    #pragma unroll
    for (int k = 1; k < 16; k <<= 1) vmax = max(vmax, __shfl_xor(vmax, k, 16));
    if (vmax < 0) return;

    const float4* xp = (const float4*)
        (x + (((size_t)((b * NN_ + n) * ND_ + d) * NFH) * NFW + w) * NC) + l;
    const int HSTRIDE = NFW * (NC / 4);
    #pragma unroll
    for (int j = 0; j < 8; ++j) {
        if (idx8[j] >= 0) {
            float4 v = xp[(hh * 8 + j) * HSTRIDE];
            int bb = idx8[j] / NXY, xy = idx8[j] % NXY;
            float* o = dst + ((size_t)(bb * NC + l * 4)) * NXY + xy;
            hw_fadd(o,           v.x);
            hw_fadd(o + NXY,     v.y);
            hw_fadd(o + 2 * NXY, v.z);
            hw_fadd(o + 3 * NXY, v.w);
        }
    }
}

extern "C" void kernel_launch(void* const* d_in, const int* in_sizes, int n_in,
                              void* d_out, int out_size, void* d_ws, size_t ws_size,
                              hipStream_t stream) {
    (void)in_sizes; (void)n_in; (void)out_size;
    const float* x          = (const float*)d_in[0];
    const float* rots       = (const float*)d_in[1];
    const float* trans      = (const float*)d_in[2];
    const float* intrins    = (const float*)d_in[3];
    const float* post_rots  = (const float*)d_in[4];
    const float* post_trans = (const float*)d_in[5];
    float* out = (float*)d_out;

    // ws layout (colsum first for float4 alignment):
    // colsum [NCOL*64 f] | cnt [NCELL i] | lists [NCELL*CAP u] | aux [NCOL u] | mats [1024 f]
    const size_t colsum_f = (size_t)NCOL * NC;                    // 2,770,944 floats
    const size_t need = (colsum_f + NCELL * (size_t)(CAP + 1) + NCOL + 1024) * 4;

    if (ws_size >= need) {
        float4*   colsum = (float4*)d_ws;
        int*      cnt    = (int*)((float*)d_ws + colsum_f);
        unsigned* lists  = (unsigned*)(cnt + NCELL);
        unsigned* aux    = lists + (size_t)NCELL * CAP;
        float*    mats   = (float*)(aux + NCOL);
        setup_kernel<<<1, 32, 0, stream>>>(rots, trans, intrins, post_rots, post_trans, mats);
        hipMemsetAsync(cnt, 0, (size_t)NCELL * sizeof(int), stream);   // ws re-poisoned each call
        colsum_build<<<NCOL / 16, 256, 0, stream>>>(x, mats, cnt, lists, aux, colsum);
        gather_bev<<<dim3(NXY / 64, NB), 256, 0, stream>>>(x, cnt, lists, aux, colsum, out);
    } else {
        float* mats = (float*)d_ws;   // 576 floats
        setup_kernel<<<1, 32, 0, stream>>>(rots, trans, intrins, post_rots, post_trans, mats);
        hipMemsetAsync(out, 0, (size_t)NB * NC * NXY * sizeof(float), stream);
        col_pool_direct<<<NCOL / 8, 256, 0, stream>>>(x, mats, out);
    }
}

// Round 8
// 288.182 us; speedup vs baseline: 1.0606x; 1.0606x over previous
//
#include <hip/hip_runtime.h>
#include <cstddef>

// ---------------- problem constants (match reference) ----------------
#define NB   4
#define NN_  6
#define ND_  41
#define NFH  16
#define NFW  44
#define NC   64
#define NX0_ 200
#define NX1_ 200
#define NXY  (NX0_ * NX1_)                 // 40000
#define NCOL (NB * NN_ * ND_ * NFW)        // 43296 columns (each = 16 vertical pixels)
#define NSLICE (NB * NN_ * ND_)            // 984 (b,n,d) slices, each 180 KB contiguous

// 3x3 inverse via adjugate. Exact in f32 for these inputs (validated).
__device__ __forceinline__ void inv3(const float* a, float* inv) {
    float c00 = __fsub_rn(__fmul_rn(a[4], a[8]), __fmul_rn(a[5], a[7]));
    float c01 = __fsub_rn(__fmul_rn(a[5], a[6]), __fmul_rn(a[3], a[8]));
    float c02 = __fsub_rn(__fmul_rn(a[3], a[7]), __fmul_rn(a[4], a[6]));
    float det = __fadd_rn(__fadd_rn(__fmul_rn(a[0], c00), __fmul_rn(a[1], c01)),
                          __fmul_rn(a[2], c02));
    inv[0] = __fdiv_rn(c00, det);
    inv[1] = __fdiv_rn(__fsub_rn(__fmul_rn(a[2], a[7]), __fmul_rn(a[1], a[8])), det);
    inv[2] = __fdiv_rn(__fsub_rn(__fmul_rn(a[1], a[5]), __fmul_rn(a[2], a[4])), det);
    inv[3] = __fdiv_rn(c01, det);
    inv[4] = __fdiv_rn(__fsub_rn(__fmul_rn(a[0], a[8]), __fmul_rn(a[2], a[6])), det);
    inv[5] = __fdiv_rn(__fsub_rn(__fmul_rn(a[2], a[3]), __fmul_rn(a[0], a[5])), det);
    inv[6] = __fdiv_rn(c02, det);
    inv[7] = __fdiv_rn(__fsub_rn(__fmul_rn(a[1], a[6]), __fmul_rn(a[0], a[7])), det);
    inv[8] = __fdiv_rn(__fsub_rn(__fmul_rn(a[0], a[4]), __fmul_rn(a[1], a[3])), det);
}

__global__ void setup_kernel(const float* __restrict__ rots,
                             const float* __restrict__ trans,
                             const float* __restrict__ intrins,
                             const float* __restrict__ post_rots,
                             const float* __restrict__ post_trans,
                             float* __restrict__ mats) {
    int t = threadIdx.x;
    if (t >= NB * NN_) return;
    const float* R  = rots      + t * 9;
    const float* K  = intrins   + t * 9;
    const float* PR = post_rots + t * 9;
    float Kinv[9], Pinv[9];
    inv3(K, Kinv);
    inv3(PR, Pinv);
    float* o = mats + t * 24;
    for (int i = 0; i < 3; ++i)
        for (int k = 0; k < 3; ++k) {
            float s = __fmul_rn(R[i * 3 + 0], Kinv[0 * 3 + k]);
            s = __fadd_rn(s, __fmul_rn(R[i * 3 + 1], Kinv[1 * 3 + k]));
            s = __fadd_rn(s, __fmul_rn(R[i * 3 + 2], Kinv[2 * 3 + k]));
            o[i * 3 + k] = s;
        }
    for (int i = 0; i < 9; ++i) o[9 + i] = Pinv[i];
    o[18] = trans[t * 3 + 0];
    o[19] = trans[t * 3 + 1];
    o[20] = trans[t * 3 + 2];
    o[21] = post_trans[t * 3 + 0];
    o[22] = post_trans[t * 3 + 1];
    o[23] = post_trans[t * 3 + 2];
}

// Fire-and-forget hardware FP32 atomic add (no return value -> no CAS loop).
__device__ __forceinline__ void hw_fadd(float* p, float v) {
    asm volatile("global_atomic_add_f32 %0, %1, off" : : "v"(p), "v"(v) : "memory");
}

// Voxel flat index (b*NXY + i0*NX1 + i1) for point (b,n,d,h,w), or -1.
// Numerics IDENTICAL to the passing rounds.
__device__ __forceinline__ int compute_idx(int b, int n, int d, int h, int w,
                                           const float* __restrict__ mats) {
    const float* mp = mats + (b * NN_ + n) * 24;

    float u   = (w == NFW - 1) ? 703.0f : (float)((double)w * (703.0 / 43.0));
    float v   = __fmul_rn((float)h, 17.0f);   // 255/15 == 17 exactly
    float dep = (float)(4 + d);               // arange(4,45,1): exact ints

    float f0 = __fsub_rn(u, mp[21]);
    float f1 = __fsub_rn(v, mp[22]);
    float f2 = __fsub_rn(dep, mp[23]);

    float q0 = __fadd_rn(__fadd_rn(__fmul_rn(mp[9],  f0), __fmul_rn(mp[10], f1)), __fmul_rn(mp[11], f2));
    float q1 = __fadd_rn(__fadd_rn(__fmul_rn(mp[12], f0), __fmul_rn(mp[13], f1)), __fmul_rn(mp[14], f2));
    float q2 = __fadd_rn(__fadd_rn(__fmul_rn(mp[15], f0), __fmul_rn(mp[16], f1)), __fmul_rn(mp[17], f2));

    float r0 = __fmul_rn(q0, q2);
    float r1 = __fmul_rn(q1, q2);

    float g0 = __fadd_rn(__fadd_rn(__fadd_rn(__fmul_rn(mp[0], r0), __fmul_rn(mp[1], r1)), __fmul_rn(mp[2], q2)), mp[18]);
    float g1 = __fadd_rn(__fadd_rn(__fadd_rn(__fmul_rn(mp[3], r0), __fmul_rn(mp[4], r1)), __fmul_rn(mp[5], q2)), mp[19]);
    float g2 = __fadd_rn(__fadd_rn(__fadd_rn(__fmul_rn(mp[6], r0), __fmul_rn(mp[7], r1)), __fmul_rn(mp[8], q2)), mp[20]);

    float s0 = __fdiv_rn(__fsub_rn(g0, -50.0f), 0.5f);
    float s1 = __fdiv_rn(__fsub_rn(g1, -50.0f), 0.5f);
    float s2 = __fdiv_rn(__fsub_rn(g2, -10.0f), 20.0f);
    s0 = fminf(fmaxf(s0, -1e6f), 1e6f);
    s1 = fminf(fmaxf(s1, -1e6f), 1e6f);
    s2 = fminf(fmaxf(s2, -1e6f), 1e6f);
    int i0 = (int)s0;   // trunc toward zero == jnp.trunc().astype(int32)
    int i1 = (int)s1;
    int i2 = (int)s2;
    if (i0 >= 0 && i0 < NX0_ && i1 >= 0 && i1 < NX1_ && i2 >= 0 && i2 < 1)
        return b * NXY + i0 * NX1_ + i1;
    return -1;
}

// Per-column metadata: cell (or -1 dropped / -3 h-dependent) + 16-bit h mask.
// 16-lane group per column, lane = h (validated butterfly). No x access.
__global__ __launch_bounds__(256) void build_meta(const float* __restrict__ mats,
                                                  int2* __restrict__ colmeta) {
    int cid = blockIdx.x * 16 + (threadIdx.x >> 4);    // NCOL = 2706*16 exactly
    int l   = threadIdx.x & 15;
    int w = cid % NFW; int t = cid / NFW;
    int d = t % ND_;   t /= ND_;
    int n = t % NN_;   int b = t / NN_;

    int myidx = compute_idx(b, n, d, l, w, mats);      // h = l

    int vm   = (myidx >= 0) ? (1 << l) : 0;
    int vmin = (myidx >= 0) ? myidx : 0x7fffffff;
    int vmax = myidx;
    #pragma unroll
    for (int k = 1; k < 16; k <<= 1) {
        vm  |= __shfl_xor(vm,  k, 16);
        vmin = min(vmin, __shfl_xor(vmin, k, 16));
        vmax = max(vmax, __shfl_xor(vmax, k, 16));
    }
    if (l == 0) {
        int cell;
        if (vmax < 0)            { cell = -1; vm = 0; }   // whole column dropped
        else if (vmin == vmax)   { cell = vmax; }         // the real path
        else                     { cell = -3; }           // h-dependent (unreachable)
        colmeta[cid] = make_int2(cell, vm);
    }
}

// The x-read engine, rebuilt around x's NATIVE layout. One 704-thread block
// per (b,n,d) slice (180 KB contiguous). Thread t owns (w = t/16, c4 = t&15);
// each h-row read is 704 consecutive float4 = 11264 B, fully coalesced per
// instruction — vs the column-walk pattern (16 strided 256 B segments/group)
// that every prior x-touching kernel used and that never exceeded ~1.5 TB/s.
// Dropped columns (~50%) skip their loads -> FETCH stays ~88 MB. Masked
// h-sum replicates R7's exact (passing) accumulation tree. Scatter = R2's
// validated contiguous 256 B atomic quad into acc[B][XY][C].
__global__ __launch_bounds__(704) void colsum_scatter(const float* __restrict__ x,
                                                      const int2* __restrict__ colmeta,
                                                      const float* __restrict__ mats,
                                                      float* __restrict__ acc) {
    __shared__ int2 smeta[NFW];
    int slice = blockIdx.x;                    // (b*NN+n)*ND + d
    int t = threadIdx.x;                       // 0..703
    if (t < NFW) smeta[t] = colmeta[slice * NFW + t];
    __syncthreads();

    int w  = t >> 4;
    int c4 = t & 15;
    int2 meta = smeta[w];
    int cell = meta.x;
    unsigned vm = (unsigned)meta.y;
    bool multi = (cell == -3);
    if (vm == 0 && !multi) return;             // dropped column: no loads

    const float4* xp = (const float4*)(x + (size_t)slice * (NFH * NFW * NC)) + t;
    const int RS = NFW * (NC / 4);             // 704 float4 per h row

    if (__builtin_expect(!multi, 1)) {
        // masked h-sum, replicating the validated tree:
        // ((h0+h2+h4+h6)+(h1+h3+h5+h7)) + ((h8+..)+(h9+..))
        float4 v[8];
        float4 A0 = make_float4(0.f, 0.f, 0.f, 0.f);
        float4 A1 = make_float4(0.f, 0.f, 0.f, 0.f);
        #pragma unroll
        for (int j = 0; j < 8; ++j) v[j] = xp[j * RS];
        #pragma unroll
        for (int j = 0; j < 8; j += 2) {
            float m0 = ((vm >> j) & 1) ? 1.0f : 0.0f;
            float m1 = ((vm >> (j + 1)) & 1) ? 1.0f : 0.0f;
            A0.x += v[j].x * m0;     A0.y += v[j].y * m0;
            A0.z += v[j].z * m0;     A0.w += v[j].w * m0;
            A1.x += v[j + 1].x * m1; A1.y += v[j + 1].y * m1;
            A1.z += v[j + 1].z * m1; A1.w += v[j + 1].w * m1;
        }
        float4 s0 = make_float4(A0.x + A1.x, A0.y + A1.y, A0.z + A1.z, A0.w + A1.w);

        float4 B0 = make_float4(0.f, 0.f, 0.f, 0.f);
        float4 B1 = make_float4(0.f, 0.f, 0.f, 0.f);
        #pragma unroll
        for (int j = 0; j < 8; ++j) v[j] = xp[(8 + j) * RS];
        #pragma unroll
        for (int j = 0; j < 8; j += 2) {
            float m0 = ((vm >> (8 + j)) & 1) ? 1.0f : 0.0f;
            float m1 = ((vm >> (9 + j)) & 1) ? 1.0f : 0.0f;
            B0.x += v[j].x * m0;     B0.y += v[j].y * m0;
            B0.z += v[j].z * m0;     B0.w += v[j].w * m0;
            B1.x += v[j + 1].x * m1; B1.y += v[j + 1].y * m1;
            B1.z += v[j + 1].z * m1; B1.w += v[j + 1].w * m1;
        }
        float4 s1 = make_float4(B0.x + B1.x, B0.y + B1.y, B0.z + B1.z, B0.w + B1.w);

        float* o = acc + (size_t)cell * NC + (c4 << 2);   // contiguous 256 B/cell
        hw_fadd(o,     s0.x + s1.x);
        hw_fadd(o + 1, s0.y + s1.y);
        hw_fadd(o + 2, s0.z + s1.z);
        hw_fadd(o + 3, s0.w + s1.w);
    } else {
        // safety net (h-dependent cells; provably unreachable for these inputs)
        int d = slice % ND_; int r = slice / ND_;
        int n = r % NN_;     int b = r / NN_;
        for (int h = 0; h < 16; ++h) {
            int ch = compute_idx(b, n, d, h, w, mats);
            if (ch >= 0) {
                float4 vv = xp[h * RS];
                float* o = acc + (size_t)ch * NC + (c4 << 2);
                hw_fadd(o,     vv.x);
                hw_fadd(o + 1, vv.y);
                hw_fadd(o + 2, vv.z);
                hw_fadd(o + 3, vv.w);
            }
        }
    }
}

// ws [B][XY][C]  ->  out [B][C][XY].  (Unchanged, validated rounds 2-3.)
// 64 cells x 64 channels tile, XOR-swizzled float4 slots (<=2-way banks =
// free). Coalesced float4 on both sides; writes every out element ->
// replaces the output memset.
__global__ __launch_bounds__(256) void transpose_ws(const float* __restrict__ ws,
                                                    float* __restrict__ out) {
    __shared__ float4 tile[64 * 16];   // [cell][c4 ^ ((cell>>2)&15)]
    int b   = blockIdx.y;
    int xy0 = blockIdx.x * 64;

    const float4* src = (const float4*)(ws + ((size_t)b * NXY + xy0) * NC);
    #pragma unroll
    for (int s = 0; s < 4; ++s) {
        int f  = s * 256 + threadIdx.x;    // 0..1023 float4s
        int i  = f >> 4;                   // cell 0..63
        int c4 = f & 15;                   // channel quad 0..15
        tile[i * 16 + (c4 ^ ((i >> 2) & 15))] = src[f];
    }
    __syncthreads();

    int l  = threadIdx.x & 63;
    int wv = threadIdx.x >> 6;
    int q  = l & 15;                       // cell quad -> i0 = 4q
    int lh = l >> 4;                       // sub-channel 0..3
    int i0 = q << 2;
    #pragma unroll
    for (int s = 0; s < 4; ++s) {
        int c  = s * 16 + wv * 4 + lh;     // covers 0..63 exactly once
        int c4 = c >> 2, cr = c & 3;
        float4 v;
        v.x = ((const float*)&tile[(i0 + 0) * 16 + (c4 ^ q)])[cr];
        v.y = ((const float*)&tile[(i0 + 1) * 16 + (c4 ^ q)])[cr];
        v.z = ((const float*)&tile[(i0 + 2) * 16 + (c4 ^ q)])[cr];
        v.w = ((const float*)&tile[(i0 + 3) * 16 + (c4 ^ q)])[cr];
        *(float4*)(out + ((size_t)(b * NC + c)) * NXY + xy0 + i0) = v;
    }
}

// ---------------- fallback (ws too small): direct-atomic path ----------------
__global__ __launch_bounds__(256) void col_pool_direct(const float* __restrict__ x,
                                                       const float* __restrict__ mats,
                                                       float* __restrict__ dst) {
    int cid = blockIdx.x * 8 + (threadIdx.x >> 5);
    int sub = threadIdx.x & 31;
    int l   = sub & 15;
    int hh  = sub >> 4;
    int w = cid % NFW; int t = cid / NFW;
    int d = t % ND_;   t /= ND_;
    int n = t % NN_;   int b = t / NN_;

    int myidx = compute_idx(b, n, d, l, w, mats);
    int idx8[8];
    #pragma unroll
    for (int j = 0; j < 8; ++j) idx8[j] = __shfl(myidx, hh * 8 + j, 32);

    int vmax = myidx;
    #pragma unroll
    for (int k = 1; k < 16; k <<= 1) vmax = max(vmax, __shfl_xor(vmax, k, 16));
    if (vmax < 0) return;

    const float4* xp = (const float4*)
        (x + (((size_t)((b * NN_ + n) * ND_ + d) * NFH) * NFW + w) * NC) + l;
    const int HSTRIDE = NFW * (NC / 4);
    #pragma unroll
    for (int j = 0; j < 8; ++j) {
        if (idx8[j] >= 0) {
            float4 v = xp[(hh * 8 + j) * HSTRIDE];
            int bb = idx8[j] / NXY, xy = idx8[j] % NXY;
            float* o = dst + ((size_t)(bb * NC + l * 4)) * NXY + xy;
            hw_fadd(o,           v.x);
            hw_fadd(o + NXY,     v.y);
            hw_fadd(o + 2 * NXY, v.z);
            hw_fadd(o + 3 * NXY, v.w);
        }
    }
}

extern "C" void kernel_launch(void* const* d_in, const int* in_sizes, int n_in,
                              void* d_out, int out_size, void* d_ws, size_t ws_size,
                              hipStream_t stream) {
    (void)in_sizes; (void)n_in; (void)out_size;
    const float* x          = (const float*)d_in[0];
    const float* rots       = (const float*)d_in[1];
    const float* trans      = (const float*)d_in[2];
    const float* intrins    = (const float*)d_in[3];
    const float* post_rots  = (const float*)d_in[4];
    const float* post_trans = (const float*)d_in[5];
    float* out = (float*)d_out;

    // ws layout: acc [B*XY*C floats] | colmeta [NCOL int2] | mats [1024 floats]
    const size_t acc_floats = (size_t)NB * NXY * NC;               // 10,240,000
    const size_t need = (acc_floats + (size_t)NCOL * 2 + 1024) * sizeof(float);  // ~41.3 MB

    if (ws_size >= need) {
        float* acc     = (float*)d_ws;
        int2*  colmeta = (int2*)(acc + acc_floats);                // 8 B aligned
        float* mats    = (float*)(colmeta + NCOL);
        setup_kernel<<<1, 32, 0, stream>>>(rots, trans, intrins, post_rots, post_trans, mats);
        hipMemsetAsync(acc, 0, acc_floats * sizeof(float), stream);   // ws re-poisoned each call
        build_meta<<<NCOL / 16, 256, 0, stream>>>(mats, colmeta);
        colsum_scatter<<<NSLICE, 704, 0, stream>>>(x, colmeta, mats, acc);
        transpose_ws<<<dim3(NXY / 64, NB), 256, 0, stream>>>(acc, out);
    } else {
        float* mats = (float*)d_ws;   // 576 floats
        setup_kernel<<<1, 32, 0, stream>>>(rots, trans, intrins, post_rots, post_trans, mats);
        hipMemsetAsync(out, 0, (size_t)NB * NC * NXY * sizeof(float), stream);
        col_pool_direct<<<NCOL / 8, 256, 0, stream>>>(x, mats, out);
    }
}